// Round 11
// baseline (288.049 us; speedup 1.0000x reference)
//
#include <hip/hip_runtime.h>
#include <float.h>

// SearchTransfer MI355X — R21: 4-blocks-per-CU GEMM (concurrency step 2).
// R20 measured: 1->2 blocks/CU raised DMA rate 170->110 cyc/KB-instr
// (x1.55) on x1.5 bytes -> net win. This round: 256-thread blocks (4 waves
// 2x2), tile 128x128, LDS 2x16KB=32KB, __launch_bounds__(256,4) with 124
// regs -> 4 blocks/CU co-resident. Bytes x1.33 (830MB); if rate scales
// ~x1.5 again (~73 cyc/instr), k_mfma ~99us. pv granularity 128 rows
// (NRT=72): ascending merge over finer tiles is bit-identical (first-wins
// = ascending global row). k_merge/k_fix: NRT 36->72 mechanical update.
// k_pack2/k_fold unchanged (controls).
// B=2, C=16, H=W=96, k=3,pad=1,stride=1, lv=2. L=9216, KF=144.
// out = [T_org (2*16*192*192 f32), S (2*9216 as f32)]

#define BATCH 2
#define CCH   16
#define HH    96
#define WW    96
#define LP    9216
#define KF    144
#define K3    160      // 5 chunks x 32 k' (hi f16 only; k'>=144 zero-pad)
#define OH    192
#define OW    192
#define NRT   72       // row tiles of 128 (pv granularity)
#define NCB   72       // col tiles of 128

typedef _Float16 f16;
typedef __attribute__((ext_vector_type(8))) _Float16 f16x8;
typedef __attribute__((ext_vector_type(4))) float    f32x4;

__device__ __forceinline__ void async16(const void* g, void* l) {
    __builtin_amdgcn_global_load_lds(
        (const __attribute__((address_space(1))) void*)g,
        (__attribute__((address_space(3))) void*)l, 16, 0, 0);
}

// ---------------------------------------------------- fused norm + pack ----
// UNCHANGED from R20 (parallel norm + nflag zeroing). Row-major f16 rows
// (row * K3), granules g = k' 8g..8g+7.
__global__ __launch_bounds__(256) void k_pack2(
        const float* __restrict__ ref, const float* __restrict__ lr,
        float* __restrict__ rinv, float* __restrict__ bns,
        f16* __restrict__ Abig, f16* __restrict__ Bbig,
        int* __restrict__ nflag) {
    __shared__ float imgS[CCH][3][26];   // x origin at global xi = q*24-1
    __shared__ float pnorm[24][8];
    __shared__ float scl[24];
    int py = blockIdx.x, b = blockIdx.y;
    int side = blockIdx.z >> 2, q = blockIdx.z & 3;
    int tid = threadIdx.x;
    if (py == 0 && b == 0 && blockIdx.z == 0 && tid == 0) *nflag = 0;
    const float* img = (side ? lr : ref) + (size_t)b * CCH * HH * WW;

    for (int i = tid; i < CCH * 3 * 26; i += 256) {
        int c = i / 78, rem = i - c * 78;
        int rr = rem / 26, xx = rem - rr * 26;
        int y = py + rr - 1, xi = q * 24 - 1 + xx;
        float v = 0.f;
        if ((unsigned)y < (unsigned)HH && (unsigned)xi < (unsigned)WW)
            v = img[(c * HH + y) * WW + xi];
        imgS[c][rr][xx] = v;
    }
    __syncthreads();

    if (tid < 192) {                     // N1: partial norms
        int pxl = tid >> 3, part = tid & 7;
        float s = 0.f;
        #pragma unroll
        for (int cc = 0; cc < 2; ++cc) {
            int c = part * 2 + cc;
            #pragma unroll
            for (int dy = 0; dy < 3; ++dy)
                #pragma unroll
                for (int dx = 0; dx < 3; ++dx) {
                    float v = imgS[c][dy][pxl + dx];   // 0 when OOB: exact
                    s += v * v;
                }
        }
        pnorm[pxl][part] = s;
    }
    __syncthreads();

    if (tid < 24) {                      // N2: deterministic reduce
        int pxl = tid;
        float s = 0.f;
        #pragma unroll
        for (int p = 0; p < 8; ++p) s += pnorm[pxl][p];
        int gl = b * LP + py * 96 + q * 24 + pxl;
        if (side) { bns[gl] = 1024.0f * sqrtf(s); scl[pxl] = 1024.0f; }
        else { float r = 1.0f / fmaxf(sqrtf(s), 1e-12f); rinv[gl] = r; scl[pxl] = 1024.0f * r; }
    }
    __syncthreads();

    f16* dstb = (side ? Bbig : Abig) + (size_t)(b * LP + py * 96 + q * 24) * K3;
    for (int i = tid; i < 24 * 20; i += 256) {          // 20 granules/row
        int pxl = i / 20, g = i - pxl * 20;
        int f0 = g * 8;
        float sc = scl[pxl];
        f16x8 o;
        #pragma unroll
        for (int e = 0; e < 8; ++e) {
            int f = f0 + e;                             // 0..159 (>=144 pad)
            float v = 0.f;
            if (f < KF) {
                int c = f / 9, r9 = f - c * 9;
                int dy = r9 / 3, dx = r9 - dy * 3;
                v = imgS[c][dy][pxl + dx] * sc;
            }
            o[e] = (f16)v;
        }
        *(f16x8*)(dstb + (size_t)pxl * K3 + g * 8) = o;
    }
}

// -------------------------------------------------- MFMA GEMM + top-2 ------
// R21: 256 threads, 4 waves (wr=w&1 row-half, wc=w>>1 col-half), tile
// 128x128. Staging per chunk = A 128 + B 128 rows = 16 x 16-row DMA instrs
// (4/wave). LDS buffer 16KB = 128 lines x 128B: A lines 0..63, B 64..127
// (64B rows, 2 rows/line, granule XOR). R10 sync skeleton. 4 blocks/CU.
__global__ __launch_bounds__(256, 4) void k_mfma(
        const f16* __restrict__ Abig, const f16* __restrict__ Bbig,
        float* __restrict__ pv1, int* __restrict__ pi1, float* __restrict__ pv2) {
    __shared__ f16 smem[2][8192];      // 2 x 16 KB
    int tid = threadIdx.x, lane = tid & 63, w = tid >> 6;   // w: 0..3
    int wr = w & 1, wc = w >> 1;       // row-half / col-half
    int l15 = lane & 15, quad = lane >> 4;

    int i = blockIdx.x;                // 0..10367
    int xcd = i & 7, slot = i >> 3;    // slot 0..1295
    int cb = slot / 18;                // col tile 0..71 (major)
    int brt = xcd * 18 + (slot - cb * 18); // 0..143
    int b = brt / NRT, rt = brt - b * NRT;
    int r0 = rt * 128, c0 = cb * 128;

    // DMA lane map (16 rows/instr, 2 rows per 128-B line, granule XOR):
    int ri  = ((lane >> 3) << 1) | ((lane >> 2) & 1);
    int qsw = (lane & 3) ^ ((lane >> 3) & 3);
    const f16* gsrc[4];
    int ldsbyte[4];
    #pragma unroll
    for (int j = 0; j < 4; ++j) {
        int G = w * 4 + j;             // 0..15
        int row16 = G * 16 + ri;       // 0..255: A rows 0..127, B rows 128..255
        const f16* base = (row16 < 128)
            ? Abig + (size_t)(b * LP + r0 + row16) * K3
            : Bbig + (size_t)(b * LP + c0 + (row16 - 128)) * K3;
        gsrc[j] = base + qsw * 8;
        ldsbyte[j] = G * 1024;         // 16 rows * 64 B
    }
    // ds_read offsets: row r -> line r>>1, half r&1, granule quad^(line&3).
    int l2 = l15 >> 1, lo1 = l15 & 1;
    int gsel = (quad ^ (l2 & 3)) * 16;
    int abyte[4], bbyte[4];
    #pragma unroll
    for (int t = 0; t < 4; ++t) {
        abyte[t] = (wr * 32 + t * 8 + l2) * 128 + lo1 * 64 + gsel;        // lines 0..63
        bbyte[t] = (64 + wc * 32 + t * 8 + l2) * 128 + lo1 * 64 + gsel;   // lines 64..127
    }

    f32x4 acc[4][4];
    #pragma unroll
    for (int ii = 0; ii < 4; ++ii)
        #pragma unroll
        for (int j = 0; j < 4; ++j) { acc[ii][j][0]=0.f; acc[ii][j][1]=0.f; acc[ii][j][2]=0.f; acc[ii][j][3]=0.f; }

    // prologue: chunk 0 -> buf 0
    #pragma unroll
    for (int j = 0; j < 4; ++j) async16(gsrc[j], (char*)smem[0] + ldsbyte[j]);

    for (int ch = 0; ch < 5; ++ch) {
        __syncthreads();               // drains own DMA; buf[ch&1] ready
        if (ch < 4) {
            #pragma unroll
            for (int j = 0; j < 4; ++j)
                async16(gsrc[j] + (ch + 1) * 32, (char*)smem[(ch + 1) & 1] + ldsbyte[j]);
        }
        const char* buf = (const char*)smem[ch & 1];
        f16x8 af[4], bf[4];
        #pragma unroll
        for (int t = 0; t < 4; ++t) af[t] = *(const f16x8*)(buf + abyte[t]);
        #pragma unroll
        for (int t = 0; t < 4; ++t) bf[t] = *(const f16x8*)(buf + bbyte[t]);
        #pragma unroll
        for (int rtt = 0; rtt < 4; ++rtt)
            #pragma unroll
            for (int ct = 0; ct < 4; ++ct)
                acc[rtt][ct] = __builtin_amdgcn_mfma_f32_16x16x32_f16(af[rtt], bf[ct], acc[rtt][ct], 0, 0, 0);
    }
    __syncthreads();                   // all smem reads done -> overlay scratch

    float* sv1 = (float*)smem;                         // [2][128]
    int*   si1 = (int*)  ((char*)smem + 1024);
    float* sv2 = (float*)((char*)smem + 2048);

    int rbase = r0 + wr * 64 + (quad << 2);
    #pragma unroll
    for (int ct = 0; ct < 4; ++ct) {
        float v1 = -FLT_MAX, v2 = -FLT_MAX; int i1 = 0;
        #pragma unroll
        for (int rtt = 0; rtt < 4; ++rtt)
            #pragma unroll
            for (int e = 0; e < 4; ++e) {              // ascending rows; strict > = first wins
                float v = acc[rtt][ct][e];
                int rg = rbase + rtt * 16 + e;
                if (v > v1) { v2 = v1; v1 = v; i1 = rg; }
                else if (v > v2) v2 = v;
            }
        #pragma unroll
        for (int off = 16; off < 64; off <<= 1) {      // reduce over quad (rows)
            float ov1 = __shfl_xor(v1, off, 64);
            int   oi1 = __shfl_xor(i1, off, 64);
            float ov2 = __shfl_xor(v2, off, 64);
            if (ov1 > v1 || (ov1 == v1 && oi1 < i1)) { v2 = fmaxf(v1, ov2); v1 = ov1; i1 = oi1; }
            else v2 = fmaxf(v2, ov1);
        }
        if (quad == 0) {
            int col = wc * 64 + ct * 16 + l15;         // 0..127
            sv1[wr * 128 + col] = v1; si1[wr * 128 + col] = i1; sv2[wr * 128 + col] = v2;
        }
    }
    __syncthreads();
    if (tid < 128) {
        int col = tid;
        float v1 = sv1[col]; int i1 = si1[col]; float v2 = sv2[col];
        {                                              // wr=1 half (higher rows)
            float ov1 = sv1[128 + col]; int oi1 = si1[128 + col]; float ov2 = sv2[128 + col];
            if (ov1 > v1) { v2 = fmaxf(v1, ov2); v1 = ov1; i1 = oi1; }
            else v2 = fmaxf(v2, ov1);
        }
        size_t o = ((size_t)(b * NRT + rt)) * LP + c0 + col;
        pv1[o] = v1; pi1[o] = i1; pv2[o] = v2;
    }
}

// --------------------------------------------------------- merge kernel ----
// NRT=72 fine tiles; ascending rc = ascending rows -> identical semantics.
__global__ __launch_bounds__(256) void k_merge(
        const float* __restrict__ pv1, const int* __restrict__ pi1,
        const float* __restrict__ pv2, const float* __restrict__ bns,
        int* __restrict__ Sint, float* __restrict__ Sout,
        int* __restrict__ flaglist, int* __restrict__ nflag) {
    int b = blockIdx.y;
    int col = blockIdx.x * 256 + threadIdx.x;
    int gid = b * LP + col;
    float v1 = -FLT_MAX, v2 = -FLT_MAX; int i1 = 0;
    for (int rc = 0; rc < NRT; ++rc) {                 // ascending: first-wins
        size_t o = ((size_t)(b * NRT + rc)) * LP + col;
        float cv1 = pv1[o]; int ci1 = pi1[o]; float cv2 = pv2[o];
        if (cv1 > v1) { v2 = fmaxf(v1, cv2); v1 = cv1; i1 = ci1; }
        else v2 = fmaxf(v2, cv1);
    }
    Sint[gid] = i1;
    Sout[gid] = (float)i1;
    float tau = bns[gid] * 0.5f;                       // tau' = 0.5*bns
    if (v1 - v2 < tau) {
        int k = atomicAdd(nflag, 1);
        flaglist[k] = gid;
    }
}

// ----------------------------------------------------------- fix kernel ----
// NRT=72 tiles of 128 rows; threads 0..127 cover a tile's rows (128..255
// idle in compute, participate in reduce with -FLT_MAX). Semantics as R16.
__global__ __launch_bounds__(256) void k_fix(
        const float* __restrict__ refimg, const float* __restrict__ lrimg,
        const float* __restrict__ rinv, const float* __restrict__ pv1,
        const float* __restrict__ bns,
        const int* __restrict__ flaglist, const int* __restrict__ nflag,
        int* __restrict__ Sint, float* __restrict__ Sout) {
    __shared__ float bcol[KF];
    __shared__ float spv[NRT];
    __shared__ float red[4]; __shared__ int redi[4];
    int tid = threadIdx.x;
    int nf = *nflag;
    for (int fi = blockIdx.x; fi < nf; fi += gridDim.x) {
        int gid = flaglist[fi];
        int b = gid / LP, col = gid - b * LP;
        int lh = col / 96, lw = col - lh * 96;
        __syncthreads();                               // protect bcol/spv reuse
        if (tid < KF) {
            int c = tid / 9, r = tid - c * 9;
            int dy = r / 3, dx = r - dy * 3;
            int y = lh + dy - 1, x = lw + dx - 1;
            float v = 0.f;
            if ((unsigned)y < (unsigned)HH && (unsigned)x < (unsigned)WW)
                v = lrimg[((size_t)(b * CCH + c) * HH + y) * WW + x];
            bcol[tid] = v;
        }
        if (tid < NRT) spv[tid] = pv1[((size_t)(b * NRT + tid)) * LP + col];
        __syncthreads();
        float v1 = -FLT_MAX;
        for (int rc = 0; rc < NRT; ++rc) v1 = fmaxf(v1, spv[rc]);
        float thresh = v1 - bns[gid] * 0.5f;           // same tau' margin
        float best = -FLT_MAX; int bi = 0x7fffffff;
        for (int rc = 0; rc < NRT; ++rc) {             // ascending rows
            if (spv[rc] < thresh) continue;            // prune (uniform)
            if (tid < 128) {
                int row = rc * 128 + tid;
                int py = row / WW, px = row - py * WW;
                float s = 0.f;
                for (int c = 0; c < CCH; ++c) {
                    const float* ic = refimg + (size_t)(b * CCH + c) * HH * WW;
                    #pragma unroll
                    for (int dy = 0; dy < 3; ++dy) {
                        int y = py + dy - 1;
                        if ((unsigned)y >= (unsigned)HH) continue;
                        #pragma unroll
                        for (int dx = 0; dx < 3; ++dx) {
                            int x = px + dx - 1;
                            if ((unsigned)x >= (unsigned)WW) continue;
                            s = fmaf(ic[y * WW + x], bcol[c * 9 + dy * 3 + dx], s);
                        }
                    }
                }
                s *= rinv[b * LP + row];
                if (s > best || (s == best && row < bi)) { best = s; bi = row; }
            }
        }
        #pragma unroll
        for (int off = 1; off < 64; off <<= 1) {
            float ov = __shfl_xor(best, off, 64);
            int   oi = __shfl_xor(bi, off, 64);
            if (ov > best || (ov == best && oi < bi)) { best = ov; bi = oi; }
        }
        if ((tid & 63) == 0) { red[tid >> 6] = best; redi[tid >> 6] = bi; }
        __syncthreads();
        if (tid == 0) {
            float b0 = red[0]; int i0 = redi[0];
            for (int k = 1; k < 4; ++k)
                if (red[k] > b0 || (red[k] == b0 && redi[k] < i0)) { b0 = red[k]; i0 = redi[k]; }
            Sint[gid] = i0;
            Sout[gid] = (float)i0;
        }
    }
}

// ---------------------------------------------------------- fold kernel ----
// UNCHANGED from R17 (wave-uniform patch loop).
__global__ __launch_bounds__(256) void k_fold(
        const int* __restrict__ Sint, const float* __restrict__ org,
        float* __restrict__ outT) {
    __shared__ int s_S[6][6];
    int tx = blockIdx.x, ty = blockIdx.y, b = blockIdx.z;
    int x0 = tx * 8, y0 = ty * 8;
    int lhb = 4 * ty - 1; if (lhb < 0) lhb = 0;
    int lwb = 4 * tx - 1; if (lwb < 0) lwb = 0;
    int lhe = 4 * ty + 4; if (lhe > 95) lhe = 95;
    int lwe = 4 * tx + 4; if (lwe > 95) lwe = 95;
    int nh = lhe - lhb + 1, nw = lwe - lwb + 1;        // 5 or 6
    int tid = threadIdx.x;

    if (tid < 36) {
        int ph = tid / 6, pw = tid - ph * 6;
        int lh = lhb + ph, lw = lwb + pw;
        s_S[ph][pw] = (lh <= lhe && lw <= lwe) ? Sint[b * LP + lh * 96 + lw] : 0;
    }
    __syncthreads();

    int wid = tid >> 6, pix = tid & 63;
    int pyL = pix >> 3, pxL = pix & 7;
    int y = y0 + pyL, x = x0 + pxL;
    const float* orgb = org + ((size_t)b * CCH + wid * 4) * OH * OW;
    float acc[4];
    #pragma unroll
    for (int c = 0; c < 4; ++c) acc[c] = 0.f;
    for (int ph = 0; ph < nh; ++ph) {                  // wave-uniform loop
        int lh = lhb + ph;
        int dy = y + 2 - 2 * lh;                       // per lane
        for (int pw = 0; pw < nw; ++pw) {
            int lw = lwb + pw;
            int dx = x + 2 - 2 * lw;
            int s  = s_S[ph][pw];                      // uniform -> broadcast
            int sh = s / 96, sw = s - sh * 96;
            if ((unsigned)dy < 6u && (unsigned)dx < 6u) {
                int u = 2 * sh + dy - 2;
                int v = 2 * sw + dx - 2;
                if ((unsigned)u < (unsigned)OH && (unsigned)v < (unsigned)OW) {
                    const float* p = orgb + u * OW + v;
                    #pragma unroll
                    for (int c = 0; c < 4; ++c) acc[c] += p[(size_t)c * OH * OW];
                }
            }
        }
    }
    #pragma unroll
    for (int c = 0; c < 4; ++c)
        outT[(((size_t)(b * CCH + wid * 4 + c)) * OH + y) * OW + x] = acc[c];
}

// --------------------------------------------------------------- launch ----
extern "C" void kernel_launch(void* const* d_in, const int* in_sizes, int n_in,
                              void* d_out, int out_size, void* d_ws, size_t ws_size,
                              hipStream_t stream) {
    const float* lrsr  = (const float*)d_in[0];
    const float* refsr = (const float*)d_in[1];
    const float* org   = (const float*)d_in[2];

    char* ws = (char*)d_ws;
    size_t o = 0;
    float* rinv     = (float*)(ws + o); o += (size_t)BATCH * LP * 4;
    float* bns      = (float*)(ws + o); o += (size_t)BATCH * LP * 4;
    float* pv1      = (float*)(ws + o); o += (size_t)BATCH * NRT * LP * 4;
    int*   pi1      = (int*)  (ws + o); o += (size_t)BATCH * NRT * LP * 4;
    float* pv2      = (float*)(ws + o); o += (size_t)BATCH * NRT * LP * 4;
    f16*   Abig     = (f16*)  (ws + o); o += (size_t)BATCH * LP * K3 * 2;
    f16*   Bbig     = (f16*)  (ws + o); o += (size_t)BATCH * LP * K3 * 2;
    int*   Sint     = (int*)  (ws + o); o += (size_t)BATCH * LP * 4;
    int*   flaglist = (int*)  (ws + o); o += (size_t)BATCH * LP * 4;
    int*   nflag    = (int*)  (ws + o); o += 16;

    float* outT = (float*)d_out;                          // 2*16*192*192
    float* outS = outT + (size_t)BATCH * CCH * OH * OW;   // 2*9216 as f32

    k_pack2<<<dim3(96, BATCH, 8), 256, 0, stream>>>(refsr, lrsr, rinv, bns, Abig, Bbig, nflag);
    k_mfma<<<dim3(NCB * NRT * BATCH), 256, 0, stream>>>(Abig, Bbig, pv1, pi1, pv2);
    k_merge<<<dim3(LP / 256, BATCH), 256, 0, stream>>>(pv1, pi1, pv2, bns,
                                                       Sint, outS, flaglist, nflag);
    k_fix<<<dim3(768), 256, 0, stream>>>(refsr, lrsr, rinv, pv1, bns,
                                         flaglist, nflag, Sint, outS);
    k_fold<<<dim3(24, 24, BATCH), 256, 0, stream>>>(Sint, org, outT);
}

// Round 13
// 253.367 us; speedup vs baseline: 1.1369x; 1.1369x over previous
//
#include <hip/hip_runtime.h>
#include <float.h>

// SearchTransfer MI355X — R22 (resubmit; previous round was an infra
// failure, "container failed twice", no kernel evidence). Keep R21 k_mfma
// (103.5us, 4 blocks/CU, DMA rate 76 cyc/KB-instr), repair the NRT=72
// tail that cost R21 the total:
//  - k_merge: 2-stage. Block = 64 cols; wave q merges rc in [18q,18q+18)
//    ascending (first-wins), LDS partials, 64 threads combine partials in
//    ascending-q order (proven asymmetric combine) -> bit-identical
//    (v1,i1,v2); 4x parallelism, 18-deep latency chains.
//  - k_fix: row-parallel. base+=256, row=base+tid, rc=row>>7 (per-wave
//    uniform prune since waves span 64 rows within one 128-row tile);
//    identical argmax/tie-break.
// k_pack2/k_mfma/k_fold unchanged (controls).
// B=2, C=16, H=W=96, k=3,pad=1,stride=1, lv=2. L=9216, KF=144.
// out = [T_org (2*16*192*192 f32), S (2*9216 as f32)]

#define BATCH 2
#define CCH   16
#define HH    96
#define WW    96
#define LP    9216
#define KF    144
#define K3    160      // 5 chunks x 32 k' (hi f16 only; k'>=144 zero-pad)
#define OH    192
#define OW    192
#define NRT   72       // row tiles of 128 (pv granularity)
#define NCB   72       // col tiles of 128

typedef _Float16 f16;
typedef __attribute__((ext_vector_type(8))) _Float16 f16x8;
typedef __attribute__((ext_vector_type(4))) float    f32x4;

__device__ __forceinline__ void async16(const void* g, void* l) {
    __builtin_amdgcn_global_load_lds(
        (const __attribute__((address_space(1))) void*)g,
        (__attribute__((address_space(3))) void*)l, 16, 0, 0);
}

// ---------------------------------------------------- fused norm + pack ----
// UNCHANGED (parallel norm + nflag zeroing). Row-major f16 rows (row * K3),
// granules g = k' 8g..8g+7.
__global__ __launch_bounds__(256) void k_pack2(
        const float* __restrict__ ref, const float* __restrict__ lr,
        float* __restrict__ rinv, float* __restrict__ bns,
        f16* __restrict__ Abig, f16* __restrict__ Bbig,
        int* __restrict__ nflag) {
    __shared__ float imgS[CCH][3][26];   // x origin at global xi = q*24-1
    __shared__ float pnorm[24][8];
    __shared__ float scl[24];
    int py = blockIdx.x, b = blockIdx.y;
    int side = blockIdx.z >> 2, q = blockIdx.z & 3;
    int tid = threadIdx.x;
    if (py == 0 && b == 0 && blockIdx.z == 0 && tid == 0) *nflag = 0;
    const float* img = (side ? lr : ref) + (size_t)b * CCH * HH * WW;

    for (int i = tid; i < CCH * 3 * 26; i += 256) {
        int c = i / 78, rem = i - c * 78;
        int rr = rem / 26, xx = rem - rr * 26;
        int y = py + rr - 1, xi = q * 24 - 1 + xx;
        float v = 0.f;
        if ((unsigned)y < (unsigned)HH && (unsigned)xi < (unsigned)WW)
            v = img[(c * HH + y) * WW + xi];
        imgS[c][rr][xx] = v;
    }
    __syncthreads();

    if (tid < 192) {                     // N1: partial norms
        int pxl = tid >> 3, part = tid & 7;
        float s = 0.f;
        #pragma unroll
        for (int cc = 0; cc < 2; ++cc) {
            int c = part * 2 + cc;
            #pragma unroll
            for (int dy = 0; dy < 3; ++dy)
                #pragma unroll
                for (int dx = 0; dx < 3; ++dx) {
                    float v = imgS[c][dy][pxl + dx];   // 0 when OOB: exact
                    s += v * v;
                }
        }
        pnorm[pxl][part] = s;
    }
    __syncthreads();

    if (tid < 24) {                      // N2: deterministic reduce
        int pxl = tid;
        float s = 0.f;
        #pragma unroll
        for (int p = 0; p < 8; ++p) s += pnorm[pxl][p];
        int gl = b * LP + py * 96 + q * 24 + pxl;
        if (side) { bns[gl] = 1024.0f * sqrtf(s); scl[pxl] = 1024.0f; }
        else { float r = 1.0f / fmaxf(sqrtf(s), 1e-12f); rinv[gl] = r; scl[pxl] = 1024.0f * r; }
    }
    __syncthreads();

    f16* dstb = (side ? Bbig : Abig) + (size_t)(b * LP + py * 96 + q * 24) * K3;
    for (int i = tid; i < 24 * 20; i += 256) {          // 20 granules/row
        int pxl = i / 20, g = i - pxl * 20;
        int f0 = g * 8;
        float sc = scl[pxl];
        f16x8 o;
        #pragma unroll
        for (int e = 0; e < 8; ++e) {
            int f = f0 + e;                             // 0..159 (>=144 pad)
            float v = 0.f;
            if (f < KF) {
                int c = f / 9, r9 = f - c * 9;
                int dy = r9 / 3, dx = r9 - dy * 3;
                v = imgS[c][dy][pxl + dx] * sc;
            }
            o[e] = (f16)v;
        }
        *(f16x8*)(dstb + (size_t)pxl * K3 + g * 8) = o;
    }
}

// -------------------------------------------------- MFMA GEMM + top-2 ------
// UNCHANGED from R21 (103.5us). 256 threads, 4 waves (wr row-half, wc
// col-half), tile 128x128, LDS 2x16KB, 4 blocks/CU, R10 sync skeleton.
__global__ __launch_bounds__(256, 4) void k_mfma(
        const f16* __restrict__ Abig, const f16* __restrict__ Bbig,
        float* __restrict__ pv1, int* __restrict__ pi1, float* __restrict__ pv2) {
    __shared__ f16 smem[2][8192];      // 2 x 16 KB
    int tid = threadIdx.x, lane = tid & 63, w = tid >> 6;   // w: 0..3
    int wr = w & 1, wc = w >> 1;       // row-half / col-half
    int l15 = lane & 15, quad = lane >> 4;

    int i = blockIdx.x;                // 0..10367
    int xcd = i & 7, slot = i >> 3;    // slot 0..1295
    int cb = slot / 18;                // col tile 0..71 (major)
    int brt = xcd * 18 + (slot - cb * 18); // 0..143
    int b = brt / NRT, rt = brt - b * NRT;
    int r0 = rt * 128, c0 = cb * 128;

    // DMA lane map (16 rows/instr, 2 rows per 128-B line, granule XOR):
    int ri  = ((lane >> 3) << 1) | ((lane >> 2) & 1);
    int qsw = (lane & 3) ^ ((lane >> 3) & 3);
    const f16* gsrc[4];
    int ldsbyte[4];
    #pragma unroll
    for (int j = 0; j < 4; ++j) {
        int G = w * 4 + j;             // 0..15
        int row16 = G * 16 + ri;       // 0..255: A rows 0..127, B rows 128..255
        const f16* base = (row16 < 128)
            ? Abig + (size_t)(b * LP + r0 + row16) * K3
            : Bbig + (size_t)(b * LP + c0 + (row16 - 128)) * K3;
        gsrc[j] = base + qsw * 8;
        ldsbyte[j] = G * 1024;         // 16 rows * 64 B
    }
    // ds_read offsets: row r -> line r>>1, half r&1, granule quad^(line&3).
    int l2 = l15 >> 1, lo1 = l15 & 1;
    int gsel = (quad ^ (l2 & 3)) * 16;
    int abyte[4], bbyte[4];
    #pragma unroll
    for (int t = 0; t < 4; ++t) {
        abyte[t] = (wr * 32 + t * 8 + l2) * 128 + lo1 * 64 + gsel;        // lines 0..63
        bbyte[t] = (64 + wc * 32 + t * 8 + l2) * 128 + lo1 * 64 + gsel;   // lines 64..127
    }

    f32x4 acc[4][4];
    #pragma unroll
    for (int ii = 0; ii < 4; ++ii)
        #pragma unroll
        for (int j = 0; j < 4; ++j) { acc[ii][j][0]=0.f; acc[ii][j][1]=0.f; acc[ii][j][2]=0.f; acc[ii][j][3]=0.f; }

    // prologue: chunk 0 -> buf 0
    #pragma unroll
    for (int j = 0; j < 4; ++j) async16(gsrc[j], (char*)smem[0] + ldsbyte[j]);

    for (int ch = 0; ch < 5; ++ch) {
        __syncthreads();               // drains own DMA; buf[ch&1] ready
        if (ch < 4) {
            #pragma unroll
            for (int j = 0; j < 4; ++j)
                async16(gsrc[j] + (ch + 1) * 32, (char*)smem[(ch + 1) & 1] + ldsbyte[j]);
        }
        const char* buf = (const char*)smem[ch & 1];
        f16x8 af[4], bf[4];
        #pragma unroll
        for (int t = 0; t < 4; ++t) af[t] = *(const f16x8*)(buf + abyte[t]);
        #pragma unroll
        for (int t = 0; t < 4; ++t) bf[t] = *(const f16x8*)(buf + bbyte[t]);
        #pragma unroll
        for (int rtt = 0; rtt < 4; ++rtt)
            #pragma unroll
            for (int ct = 0; ct < 4; ++ct)
                acc[rtt][ct] = __builtin_amdgcn_mfma_f32_16x16x32_f16(af[rtt], bf[ct], acc[rtt][ct], 0, 0, 0);
    }
    __syncthreads();                   // all smem reads done -> overlay scratch

    float* sv1 = (float*)smem;                         // [2][128]
    int*   si1 = (int*)  ((char*)smem + 1024);
    float* sv2 = (float*)((char*)smem + 2048);

    int rbase = r0 + wr * 64 + (quad << 2);
    #pragma unroll
    for (int ct = 0; ct < 4; ++ct) {
        float v1 = -FLT_MAX, v2 = -FLT_MAX; int i1 = 0;
        #pragma unroll
        for (int rtt = 0; rtt < 4; ++rtt)
            #pragma unroll
            for (int e = 0; e < 4; ++e) {              // ascending rows; strict > = first wins
                float v = acc[rtt][ct][e];
                int rg = rbase + rtt * 16 + e;
                if (v > v1) { v2 = v1; v1 = v; i1 = rg; }
                else if (v > v2) v2 = v;
            }
        #pragma unroll
        for (int off = 16; off < 64; off <<= 1) {      // reduce over quad (rows)
            float ov1 = __shfl_xor(v1, off, 64);
            int   oi1 = __shfl_xor(i1, off, 64);
            float ov2 = __shfl_xor(v2, off, 64);
            if (ov1 > v1 || (ov1 == v1 && oi1 < i1)) { v2 = fmaxf(v1, ov2); v1 = ov1; i1 = oi1; }
            else v2 = fmaxf(v2, ov1);
        }
        if (quad == 0) {
            int col = wc * 64 + ct * 16 + l15;         // 0..127
            sv1[wr * 128 + col] = v1; si1[wr * 128 + col] = i1; sv2[wr * 128 + col] = v2;
        }
    }
    __syncthreads();
    if (tid < 128) {
        int col = tid;
        float v1 = sv1[col]; int i1 = si1[col]; float v2 = sv2[col];
        {                                              // wr=1 half (higher rows)
            float ov1 = sv1[128 + col]; int oi1 = si1[128 + col]; float ov2 = sv2[128 + col];
            if (ov1 > v1) { v2 = fmaxf(v1, ov2); v1 = ov1; i1 = oi1; }
            else v2 = fmaxf(v2, ov1);
        }
        size_t o = ((size_t)(b * NRT + rt)) * LP + c0 + col;
        pv1[o] = v1; pi1[o] = i1; pv2[o] = v2;
    }
}

// --------------------------------------------------------- merge kernel ----
// R22: 2-stage. Block = 64 cols; wave q merges rc in [18q, 18q+18)
// (ascending), partials to LDS; threads 0..63 combine partials ascending-q
// (first-wins asymmetric combine) -> bit-identical to the flat loop.
__global__ __launch_bounds__(256) void k_merge(
        const float* __restrict__ pv1, const int* __restrict__ pi1,
        const float* __restrict__ pv2, const float* __restrict__ bns,
        int* __restrict__ Sint, float* __restrict__ Sout,
        int* __restrict__ flaglist, int* __restrict__ nflag) {
    __shared__ float s1[4][64]; __shared__ int si[4][64]; __shared__ float s2[4][64];
    int b = blockIdx.y;
    int tid = threadIdx.x;
    int cl = tid & 63, qw = tid >> 6;
    int col = blockIdx.x * 64 + cl;
    float v1 = -FLT_MAX, v2 = -FLT_MAX; int i1 = 0;
    #pragma unroll 2
    for (int k = 0; k < 18; ++k) {                     // ascending rc within slice
        int rc = qw * 18 + k;
        size_t o = ((size_t)(b * NRT + rc)) * LP + col;
        float cv1 = pv1[o]; int ci1 = pi1[o]; float cv2 = pv2[o];
        if (cv1 > v1) { v2 = fmaxf(v1, cv2); v1 = cv1; i1 = ci1; }
        else v2 = fmaxf(v2, cv1);
    }
    s1[qw][cl] = v1; si[qw][cl] = i1; s2[qw][cl] = v2;
    __syncthreads();
    if (tid < 64) {
        float v1 = s1[0][tid]; int i1 = si[0][tid]; float v2 = s2[0][tid];
        #pragma unroll
        for (int q = 1; q < 4; ++q) {                  // ascending q = ascending rows
            float ov1 = s1[q][tid]; int oi1 = si[q][tid]; float ov2 = s2[q][tid];
            if (ov1 > v1) { v2 = fmaxf(v1, ov2); v1 = ov1; i1 = oi1; }
            else v2 = fmaxf(v2, ov1);
        }
        int gid = b * LP + blockIdx.x * 64 + tid;
        Sint[gid] = i1;
        Sout[gid] = (float)i1;
        float tau = bns[gid] * 0.5f;                   // tau' = 0.5*bns
        if (v1 - v2 < tau) {
            int k = atomicAdd(nflag, 1);
            flaglist[k] = gid;
        }
    }
}

// ----------------------------------------------------------- fix kernel ----
// R22: row-parallel. All 256 threads active: row = base + tid, tile
// rc = row>>7 (per-wave uniform -> uniform prune branch). Per-thread
// ascending rows + min-index reduce = identical argmax semantics.
__global__ __launch_bounds__(256) void k_fix(
        const float* __restrict__ refimg, const float* __restrict__ lrimg,
        const float* __restrict__ rinv, const float* __restrict__ pv1,
        const float* __restrict__ bns,
        const int* __restrict__ flaglist, const int* __restrict__ nflag,
        int* __restrict__ Sint, float* __restrict__ Sout) {
    __shared__ float bcol[KF];
    __shared__ float spv[NRT];
    __shared__ float red[4]; __shared__ int redi[4];
    int tid = threadIdx.x;
    int nf = *nflag;
    for (int fi = blockIdx.x; fi < nf; fi += gridDim.x) {
        int gid = flaglist[fi];
        int b = gid / LP, col = gid - b * LP;
        int lh = col / 96, lw = col - lh * 96;
        __syncthreads();                               // protect bcol/spv reuse
        if (tid < KF) {
            int c = tid / 9, r = tid - c * 9;
            int dy = r / 3, dx = r - dy * 3;
            int y = lh + dy - 1, x = lw + dx - 1;
            float v = 0.f;
            if ((unsigned)y < (unsigned)HH && (unsigned)x < (unsigned)WW)
                v = lrimg[((size_t)(b * CCH + c) * HH + y) * WW + x];
            bcol[tid] = v;
        }
        if (tid < NRT) spv[tid] = pv1[((size_t)(b * NRT + tid)) * LP + col];
        __syncthreads();
        float v1 = -FLT_MAX;
        for (int rc = 0; rc < NRT; ++rc) v1 = fmaxf(v1, spv[rc]);
        float thresh = v1 - bns[gid] * 0.5f;           // same tau' margin
        float best = -FLT_MAX; int bi = 0x7fffffff;
        for (int base = 0; base < LP; base += 256) {   // ascending rows per thread
            int row = base + tid;
            int rc = row >> 7;                         // wave-uniform tile
            if (spv[rc] < thresh) continue;            // prune
            int py = row / WW, px = row - py * WW;
            float s = 0.f;
            for (int c = 0; c < CCH; ++c) {
                const float* ic = refimg + (size_t)(b * CCH + c) * HH * WW;
                #pragma unroll
                for (int dy = 0; dy < 3; ++dy) {
                    int y = py + dy - 1;
                    if ((unsigned)y >= (unsigned)HH) continue;
                    #pragma unroll
                    for (int dx = 0; dx < 3; ++dx) {
                        int x = px + dx - 1;
                        if ((unsigned)x >= (unsigned)WW) continue;
                        s = fmaf(ic[y * WW + x], bcol[c * 9 + dy * 3 + dx], s);
                    }
                }
            }
            s *= rinv[b * LP + row];
            if (s > best || (s == best && row < bi)) { best = s; bi = row; }
        }
        #pragma unroll
        for (int off = 1; off < 64; off <<= 1) {
            float ov = __shfl_xor(best, off, 64);
            int   oi = __shfl_xor(bi, off, 64);
            if (ov > best || (ov == best && oi < bi)) { best = ov; bi = oi; }
        }
        if ((tid & 63) == 0) { red[tid >> 6] = best; redi[tid >> 6] = bi; }
        __syncthreads();
        if (tid == 0) {
            float b0 = red[0]; int i0 = redi[0];
            for (int k = 1; k < 4; ++k)
                if (red[k] > b0 || (red[k] == b0 && redi[k] < i0)) { b0 = red[k]; i0 = redi[k]; }
            Sint[gid] = i0;
            Sout[gid] = (float)i0;
        }
    }
}

// ---------------------------------------------------------- fold kernel ----
// UNCHANGED from R17 (wave-uniform patch loop).
__global__ __launch_bounds__(256) void k_fold(
        const int* __restrict__ Sint, const float* __restrict__ org,
        float* __restrict__ outT) {
    __shared__ int s_S[6][6];
    int tx = blockIdx.x, ty = blockIdx.y, b = blockIdx.z;
    int x0 = tx * 8, y0 = ty * 8;
    int lhb = 4 * ty - 1; if (lhb < 0) lhb = 0;
    int lwb = 4 * tx - 1; if (lwb < 0) lwb = 0;
    int lhe = 4 * ty + 4; if (lhe > 95) lhe = 95;
    int lwe = 4 * tx + 4; if (lwe > 95) lwe = 95;
    int nh = lhe - lhb + 1, nw = lwe - lwb + 1;        // 5 or 6
    int tid = threadIdx.x;

    if (tid < 36) {
        int ph = tid / 6, pw = tid - ph * 6;
        int lh = lhb + ph, lw = lwb + pw;
        s_S[ph][pw] = (lh <= lhe && lw <= lwe) ? Sint[b * LP + lh * 96 + lw] : 0;
    }
    __syncthreads();

    int wid = tid >> 6, pix = tid & 63;
    int pyL = pix >> 3, pxL = pix & 7;
    int y = y0 + pyL, x = x0 + pxL;
    const float* orgb = org + ((size_t)b * CCH + wid * 4) * OH * OW;
    float acc[4];
    #pragma unroll
    for (int c = 0; c < 4; ++c) acc[c] = 0.f;
    for (int ph = 0; ph < nh; ++ph) {                  // wave-uniform loop
        int lh = lhb + ph;
        int dy = y + 2 - 2 * lh;                       // per lane
        for (int pw = 0; pw < nw; ++pw) {
            int lw = lwb + pw;
            int dx = x + 2 - 2 * lw;
            int s  = s_S[ph][pw];                      // uniform -> broadcast
            int sh = s / 96, sw = s - sh * 96;
            if ((unsigned)dy < 6u && (unsigned)dx < 6u) {
                int u = 2 * sh + dy - 2;
                int v = 2 * sw + dx - 2;
                if ((unsigned)u < (unsigned)OH && (unsigned)v < (unsigned)OW) {
                    const float* p = orgb + u * OW + v;
                    #pragma unroll
                    for (int c = 0; c < 4; ++c) acc[c] += p[(size_t)c * OH * OW];
                }
            }
        }
    }
    #pragma unroll
    for (int c = 0; c < 4; ++c)
        outT[(((size_t)(b * CCH + wid * 4 + c)) * OH + y) * OW + x] = acc[c];
}

// --------------------------------------------------------------- launch ----
extern "C" void kernel_launch(void* const* d_in, const int* in_sizes, int n_in,
                              void* d_out, int out_size, void* d_ws, size_t ws_size,
                              hipStream_t stream) {
    const float* lrsr  = (const float*)d_in[0];
    const float* refsr = (const float*)d_in[1];
    const float* org   = (const float*)d_in[2];

    char* ws = (char*)d_ws;
    size_t o = 0;
    float* rinv     = (float*)(ws + o); o += (size_t)BATCH * LP * 4;
    float* bns      = (float*)(ws + o); o += (size_t)BATCH * LP * 4;
    float* pv1      = (float*)(ws + o); o += (size_t)BATCH * NRT * LP * 4;
    int*   pi1      = (int*)  (ws + o); o += (size_t)BATCH * NRT * LP * 4;
    float* pv2      = (float*)(ws + o); o += (size_t)BATCH * NRT * LP * 4;
    f16*   Abig     = (f16*)  (ws + o); o += (size_t)BATCH * LP * K3 * 2;
    f16*   Bbig     = (f16*)  (ws + o); o += (size_t)BATCH * LP * K3 * 2;
    int*   Sint     = (int*)  (ws + o); o += (size_t)BATCH * LP * 4;
    int*   flaglist = (int*)  (ws + o); o += (size_t)BATCH * LP * 4;
    int*   nflag    = (int*)  (ws + o); o += 16;

    float* outT = (float*)d_out;                          // 2*16*192*192
    float* outS = outT + (size_t)BATCH * CCH * OH * OW;   // 2*9216 as f32

    k_pack2<<<dim3(96, BATCH, 8), 256, 0, stream>>>(refsr, lrsr, rinv, bns, Abig, Bbig, nflag);
    k_mfma<<<dim3(NCB * NRT * BATCH), 256, 0, stream>>>(Abig, Bbig, pv1, pi1, pv2);
    k_merge<<<dim3(LP / 64, BATCH), 256, 0, stream>>>(pv1, pi1, pv2, bns,
                                                      Sint, outS, flaglist, nflag);
    k_fix<<<dim3(768), 256, 0, stream>>>(refsr, lrsr, rinv, pv1, bns,
                                         flaglist, nflag, Sint, outS);
    k_fold<<<dim3(24, 24, BATCH), 256, 0, stream>>>(Sint, org, outT);
}